// Round 1
// baseline (27213.400 us; speedup 1.0000x reference)
//
#include <hip/hip_runtime.h>
#include <math.h>

// Problem constants
#define BB 32
#define CC 3
#define IMG 224
#define PP 16
#define DD 768
#define NTOK 197   // 196 patches + cls
#define NPATCH 196
#define NH 12
#define DHEAD 64
#define MLPD 3072
#define NLAYER 12
#define PROJD 512
#define NCLS 1000

// ---------------------------------------------------------------------------
// Generic NT GEMM:  C[m,n] = sum_k A[m,k] * W[n,k]  (+bias)(+gelu)(+residual)
// flags: 1 = add bias, 2 = exact gelu, 4 = accumulate into C (residual add)
// 64x64 tile, K-step 16, 256 threads (16x16), 4x4 results per thread.
// ---------------------------------------------------------------------------
__global__ void gemm_nt(const float* __restrict__ A, int lda,
                        const float* __restrict__ W, int ldw,
                        const float* __restrict__ bias,
                        float* __restrict__ C, int ldc,
                        int M, int Nout, int K, int flags)
{
    __shared__ float sA[16][65];
    __shared__ float sW[16][65];
    const int tx = threadIdx.x, ty = threadIdx.y;
    const int t = ty * 16 + tx;
    const int m0 = blockIdx.y * 64, n0 = blockIdx.x * 64;
    float acc[4][4] = {};

    for (int kt = 0; kt < K; kt += 16) {
#pragma unroll
        for (int s = 0; s < 4; s++) {
            int e = t + s * 256;
            int r = e >> 4, c = e & 15;
            int gm = m0 + r;
            int gn = n0 + r;
            int gk = kt + c;
            sA[c][r] = (gm < M) ? A[(long)gm * lda + gk] : 0.f;
            sW[c][r] = (gn < Nout) ? W[(long)gn * ldw + gk] : 0.f;
        }
        __syncthreads();
#pragma unroll
        for (int kk = 0; kk < 16; kk++) {
            float a[4], b[4];
#pragma unroll
            for (int i = 0; i < 4; i++) a[i] = sA[kk][ty + 16 * i];
#pragma unroll
            for (int j = 0; j < 4; j++) b[j] = sW[kk][tx + 16 * j];
#pragma unroll
            for (int i = 0; i < 4; i++)
#pragma unroll
                for (int j = 0; j < 4; j++)
                    acc[i][j] += a[i] * b[j];
        }
        __syncthreads();
    }

#pragma unroll
    for (int i = 0; i < 4; i++) {
        int m = m0 + ty + 16 * i;
        if (m >= M) continue;
#pragma unroll
        for (int j = 0; j < 4; j++) {
            int n = n0 + tx + 16 * j;
            if (n >= Nout) continue;
            float v = acc[i][j];
            if (flags & 1) v += bias[n];
            if (flags & 2) v = 0.5f * v * (1.0f + erff(v * 0.70710678118654752f));
            long off = (long)m * ldc + n;
            if (flags & 4) C[off] += v;
            else           C[off]  = v;
        }
    }
}

// ---------------------------------------------------------------------------
// LayerNorm over last dim (768). One block (256 threads) per row.
// ---------------------------------------------------------------------------
__global__ void layernorm_rows(const float* __restrict__ X,
                               const float* __restrict__ w,
                               const float* __restrict__ b,
                               float* __restrict__ Y)
{
    const int r = blockIdx.x;
    const int t = threadIdx.x;
    const float* xr = X + (long)r * DD;
    float x0 = xr[t], x1 = xr[t + 256], x2 = xr[t + 512];
    float s = x0 + x1 + x2;
    float q = x0 * x0 + x1 * x1 + x2 * x2;
    __shared__ float rs[256], rq[256];
    rs[t] = s; rq[t] = q;
    __syncthreads();
    for (int off = 128; off > 0; off >>= 1) {
        if (t < off) { rs[t] += rs[t + off]; rq[t] += rq[t + off]; }
        __syncthreads();
    }
    float mean = rs[0] * (1.f / 768.f);
    float var = rq[0] * (1.f / 768.f) - mean * mean;
    float rstd = rsqrtf(var + 1e-5f);
    float* yr = Y + (long)r * DD;
    yr[t]       = (x0 - mean) * rstd * w[t]       + b[t];
    yr[t + 256] = (x1 - mean) * rstd * w[t + 256] + b[t + 256];
    yr[t + 512] = (x2 - mean) * rstd * w[t + 512] + b[t + 512];
}

// ---------------------------------------------------------------------------
// im2col: x (B,C,224,224) -> patches (B*196, 768), k = c*256 + ph*16 + pw
// ---------------------------------------------------------------------------
__global__ void im2col_kernel(const float* __restrict__ x, float* __restrict__ Pm)
{
    int idx = blockIdx.x * 256 + threadIdx.x;
    const int total = BB * NPATCH * DD;
    if (idx >= total) return;
    int row = idx / DD;       // b*196 + p
    int k = idx - row * DD;
    int b = row / NPATCH;
    int p = row - b * NPATCH;
    int py = p / 14, px = p - py * 14;
    int c = k >> 8;           // /256
    int rr = k & 255;
    int ph = rr >> 4, pw = rr & 15;
    Pm[idx] = x[(((long)b * CC + c) * IMG + (py * 16 + ph)) * IMG + (px * 16 + pw)];
}

// ---------------------------------------------------------------------------
// assemble: H[b,n,:] = (n==0 ? cls : patch_out[b,n-1,:]) + pos_embed[n,:]
// ---------------------------------------------------------------------------
__global__ void assemble_kernel(const float* __restrict__ tmp,
                                const float* __restrict__ cls,
                                const float* __restrict__ pos,
                                float* __restrict__ Hb)
{
    int idx = blockIdx.x * 256 + threadIdx.x;
    const int total = BB * NTOK * DD;
    if (idx >= total) return;
    int row = idx / DD;
    int d = idx - row * DD;
    int b = row / NTOK;
    int n = row - b * NTOK;
    float v = (n == 0) ? cls[d] : tmp[((long)b * NPATCH + (n - 1)) * DD + d];
    Hb[idx] = v + pos[n * DD + d];
}

// ---------------------------------------------------------------------------
// attention scores: S[b,h,i,j] = 0.125 * sum_d Q[b,h,i,d]*K[b,h,j,d]
// QKV layout (B, N, 2304): Q at +h*64, K at +768+h*64, V at +1536+h*64
// ---------------------------------------------------------------------------
__global__ void attn_scores(const float* __restrict__ QKV, float* __restrict__ S)
{
    const int bh = blockIdx.z;
    const int b = bh / NH, h = bh - b * NH;
    const int i0 = blockIdx.y * 32, j0 = blockIdx.x * 32;
    __shared__ float sQ[32][65];
    __shared__ float sK[32][65];
    const int tx = threadIdx.x, ty = threadIdx.y;
    const int t = ty * 16 + tx;
    const float* Qb = QKV + (long)b * NTOK * 2304 + h * 64;
    const float* Kb = Qb + 768;
#pragma unroll
    for (int s = 0; s < 8; s++) {
        int e = t + s * 256;
        int row = e >> 6, col = e & 63;
        sQ[row][col] = (i0 + row < NTOK) ? Qb[(long)(i0 + row) * 2304 + col] : 0.f;
        sK[row][col] = (j0 + row < NTOK) ? Kb[(long)(j0 + row) * 2304 + col] : 0.f;
    }
    __syncthreads();
    float acc00 = 0.f, acc01 = 0.f, acc10 = 0.f, acc11 = 0.f;
#pragma unroll 8
    for (int k = 0; k < 64; k++) {
        float q0 = sQ[ty * 2][k],     q1 = sQ[ty * 2 + 1][k];
        float k0 = sK[tx * 2][k],     k1 = sK[tx * 2 + 1][k];
        acc00 += q0 * k0; acc01 += q0 * k1;
        acc10 += q1 * k0; acc11 += q1 * k1;
    }
    float* Sb = S + (long)bh * NTOK * NTOK;
    int i = i0 + ty * 2, j = j0 + tx * 2;
    const float sc = 0.125f;
    if (i < NTOK) {
        if (j < NTOK)     Sb[(long)i * NTOK + j]     = acc00 * sc;
        if (j + 1 < NTOK) Sb[(long)i * NTOK + j + 1] = acc01 * sc;
    }
    if (i + 1 < NTOK) {
        if (j < NTOK)     Sb[(long)(i + 1) * NTOK + j]     = acc10 * sc;
        if (j + 1 < NTOK) Sb[(long)(i + 1) * NTOK + j + 1] = acc11 * sc;
    }
}

// ---------------------------------------------------------------------------
// row softmax over 197 elements; one wave (64 lanes) per row
// ---------------------------------------------------------------------------
__global__ void softmax197(float* __restrict__ S)
{
    const long row = blockIdx.x;
    const int lane = threadIdx.x;
    float* p = S + row * NTOK;
    float v[4];
    float m = -1e30f;
#pragma unroll
    for (int k = 0; k < 4; k++) {
        int j = lane + 64 * k;
        v[k] = (j < NTOK) ? p[j] : -1e30f;
        m = fmaxf(m, v[k]);
    }
    for (int off = 32; off > 0; off >>= 1) m = fmaxf(m, __shfl_xor(m, off));
    float s = 0.f;
#pragma unroll
    for (int k = 0; k < 4; k++) { v[k] = expf(v[k] - m); s += v[k]; }
    for (int off = 32; off > 0; off >>= 1) s += __shfl_xor(s, off);
    float inv = 1.f / s;
#pragma unroll
    for (int k = 0; k < 4; k++) {
        int j = lane + 64 * k;
        if (j < NTOK) p[j] = v[k] * inv;
    }
}

// ---------------------------------------------------------------------------
// O[b,n,h*64+d] = sum_j P[b,h,i,j] * V[b,h,j,d]
// block (64,4): tx = d, ty = i within 4-row tile; LDS-staged V/S chunks
// ---------------------------------------------------------------------------
__global__ void attn_av(const float* __restrict__ S, const float* __restrict__ QKV,
                        float* __restrict__ O)
{
    const int bh = blockIdx.y;
    const int b = bh / NH, h = bh - b * NH;
    const int i0 = blockIdx.x * 4;
    const int tx = threadIdx.x, ty = threadIdx.y;
    const int t = ty * 64 + tx;
    __shared__ float sV[64][64];
    __shared__ float sS[4][64];
    const float* Vb = QKV + (long)b * NTOK * 2304 + 1536 + h * 64;
    const float* Sb = S + (long)bh * NTOK * NTOK;
    float acc = 0.f;
    for (int jc = 0; jc < 256; jc += 64) {
#pragma unroll
        for (int s = 0; s < 16; s++) {
            int e = t + s * 256;
            int row = e >> 6, col = e & 63;
            sV[row][col] = (jc + row < NTOK) ? Vb[(long)(jc + row) * 2304 + col] : 0.f;
        }
        {
            int row = t >> 6, col = t & 63;
            int i = i0 + row, j = jc + col;
            sS[row][col] = (i < NTOK && j < NTOK) ? Sb[(long)i * NTOK + j] : 0.f;
        }
        __syncthreads();
#pragma unroll 16
        for (int jj = 0; jj < 64; jj++)
            acc += sS[ty][jj] * sV[jj][tx];
        __syncthreads();
    }
    int i = i0 + ty;
    if (i < NTOK)
        O[((long)b * NTOK + i) * DD + h * 64 + tx] = acc;
}

// ---------------------------------------------------------------------------
// extract cls row (n == 0) of each batch
// ---------------------------------------------------------------------------
__global__ void extract_cls(const float* __restrict__ Hb, float* __restrict__ pooled)
{
    int idx = blockIdx.x * 256 + threadIdx.x;
    if (idx >= BB * DD) return;
    int b = idx / DD;
    int d = idx - b * DD;
    pooled[idx] = Hb[(long)b * NTOK * DD + d];
}

// ---------------------------------------------------------------------------
extern "C" void kernel_launch(void* const* d_in, const int* in_sizes, int n_in,
                              void* d_out, int out_size, void* d_ws, size_t ws_size,
                              hipStream_t stream)
{
    const float* x          = (const float*)d_in[0];
    const float* conv_w     = (const float*)d_in[1];
    const float* cls_token  = (const float*)d_in[2];
    const float* pos_embed  = (const float*)d_in[3];
    const float* ln_pre_w   = (const float*)d_in[4];
    const float* ln_pre_b   = (const float*)d_in[5];
    const float* ln1_w      = (const float*)d_in[6];
    const float* ln1_b      = (const float*)d_in[7];
    const float* qkv_w      = (const float*)d_in[8];
    const float* qkv_b      = (const float*)d_in[9];
    const float* attn_pw    = (const float*)d_in[10];
    const float* attn_pb    = (const float*)d_in[11];
    const float* ln2_w      = (const float*)d_in[12];
    const float* ln2_b      = (const float*)d_in[13];
    const float* fc_w       = (const float*)d_in[14];
    const float* fc_b       = (const float*)d_in[15];
    const float* cproj_w    = (const float*)d_in[16];
    const float* cproj_b    = (const float*)d_in[17];
    const float* ln_post_w  = (const float*)d_in[18];
    const float* ln_post_b  = (const float*)d_in[19];
    const float* proj_w     = (const float*)d_in[20];
    const float* head_w     = (const float*)d_in[21];
    const float* head_b     = (const float*)d_in[22];
    float* out = (float*)d_out;

    // workspace layout (bytes)
    const size_t SZ_X   = (size_t)BB * NTOK * DD * 4;          // 19,365,888
    const size_t SZ_BUF = (size_t)BB * NTOK * MLPD * 4;        // 77,463,552
    const size_t SZ_S   = (size_t)BB * NH * NTOK * NTOK * 4;   // 59,614,464
    char* ws = (char*)d_ws;
    float* X      = (float*)(ws);
    float* Hb     = (float*)(ws + SZ_X);
    float* BUF    = (float*)(ws + 2 * SZ_X);
    float* Sc     = (float*)(ws + 2 * SZ_X + SZ_BUF);
    float* pooled = (float*)(ws + 2 * SZ_X + SZ_BUF + SZ_S);
    float* z      = pooled + BB * DD;

    const int Mtok = BB * NTOK;   // 6304
    const dim3 thr(16, 16);

    // 1) patch embed: im2col -> GEMM -> assemble(+cls,+pos) -> ln_pre
    {
        int tot = BB * NPATCH * DD;
        im2col_kernel<<<(tot + 255) / 256, 256, 0, stream>>>(x, BUF);
        gemm_nt<<<dim3(DD / 64, (BB * NPATCH + 63) / 64), thr, 0, stream>>>(
            BUF, DD, conv_w, DD, nullptr, Sc, DD, BB * NPATCH, DD, DD, 0);
        tot = Mtok * DD;
        assemble_kernel<<<(tot + 255) / 256, 256, 0, stream>>>(Sc, cls_token, pos_embed, Hb);
        layernorm_rows<<<Mtok, 256, 0, stream>>>(Hb, ln_pre_w, ln_pre_b, X);
    }

    // 2) transformer blocks
    for (int l = 0; l < NLAYER; l++) {
        layernorm_rows<<<Mtok, 256, 0, stream>>>(X, ln1_w + l * DD, ln1_b + l * DD, Hb);
        gemm_nt<<<dim3(2304 / 64, (Mtok + 63) / 64), thr, 0, stream>>>(
            Hb, DD, qkv_w + (long)l * 2304 * DD, DD, qkv_b + l * 2304,
            BUF, 2304, Mtok, 2304, DD, 1);
        attn_scores<<<dim3(7, 7, BB * NH), thr, 0, stream>>>(BUF, Sc);
        softmax197<<<BB * NH * NTOK, 64, 0, stream>>>(Sc);
        attn_av<<<dim3((NTOK + 3) / 4, BB * NH), dim3(64, 4), 0, stream>>>(Sc, BUF, Hb);
        gemm_nt<<<dim3(DD / 64, (Mtok + 63) / 64), thr, 0, stream>>>(
            Hb, DD, attn_pw + (long)l * DD * DD, DD, attn_pb + l * DD,
            X, DD, Mtok, DD, DD, 1 | 4);
        layernorm_rows<<<Mtok, 256, 0, stream>>>(X, ln2_w + l * DD, ln2_b + l * DD, Hb);
        gemm_nt<<<dim3(MLPD / 64, (Mtok + 63) / 64), thr, 0, stream>>>(
            Hb, DD, fc_w + (long)l * MLPD * DD, DD, fc_b + l * MLPD,
            BUF, MLPD, Mtok, MLPD, DD, 1 | 2);
        gemm_nt<<<dim3(DD / 64, (Mtok + 63) / 64), thr, 0, stream>>>(
            BUF, MLPD, cproj_w + (long)l * DD * MLPD, MLPD, cproj_b + l * DD,
            X, DD, Mtok, DD, MLPD, 1 | 4);
    }

    // 3) ln_post -> cls -> proj -> head
    layernorm_rows<<<Mtok, 256, 0, stream>>>(X, ln_post_w, ln_post_b, Hb);
    extract_cls<<<(BB * DD + 255) / 256, 256, 0, stream>>>(Hb, pooled);
    gemm_nt<<<dim3(PROJD / 64, 1), thr, 0, stream>>>(
        pooled, DD, proj_w, DD, nullptr, z, PROJD, BB, PROJD, DD, 0);
    gemm_nt<<<dim3((NCLS + 63) / 64, 1), thr, 0, stream>>>(
        z, PROJD, head_w, PROJD, head_b, out, NCLS, BB, NCLS, PROJD, 1);
}

// Round 2
// 7647.943 us; speedup vs baseline: 3.5583x; 3.5583x over previous
//
#include <hip/hip_runtime.h>
#include <math.h>
#include <stdint.h>

typedef unsigned short ushort_t;
typedef unsigned int uint_t;

// Problem constants
#define BB 32
#define CC 3
#define IMG 224
#define PP 16
#define DD 768
#define NTOK 197   // 196 patches + cls
#define NPATCH 196
#define NH 12
#define DHEAD 64
#define MLPD 3072
#define NLAYER 12
#define PROJD 512
#define NCLS 1000
#define MTOK (BB * NTOK)      // 6304
#define MPAD 6400             // padded to multiple of 128

typedef __bf16 bf16x8 __attribute__((ext_vector_type(8)));
typedef float floatx4 __attribute__((ext_vector_type(4)));

__device__ __forceinline__ ushort_t f2bf(float f) {
    union { float f; uint_t u; } x; x.f = f;
    uint_t r = x.u + 0x7fff + ((x.u >> 16) & 1);
    return (ushort_t)(r >> 16);
}

// CK-style async global->LDS direct copy, 16B per lane.
__device__ __forceinline__ void async16(void* lds, const void* g) {
    auto* gp = reinterpret_cast<const __attribute__((address_space(1))) uint_t*>(
        reinterpret_cast<uintptr_t>(g));
    auto* lp = reinterpret_cast<__attribute__((address_space(3))) uint_t*>(
        reinterpret_cast<uintptr_t>(lds));
    __builtin_amdgcn_global_load_lds(gp, lp, 16, 0, 0);
}

// ---------------------------------------------------------------------------
// bf16 MFMA NT GEMM: C[m,n] = sum_k A[m,k]*W[n,k]  (A,W bf16; C fp32 or bf16)
// Tile 128x128, K-step 32, 256 threads = 4 waves each computing 64x64.
// Requires: grid.y*128 rows allocated in A and C, N % 128 == 0, K % 32 == 0.
// flags: 1 = +bias, 2 = exact gelu, 4 = fp32 accumulate into C, 8 = bf16 out
// ---------------------------------------------------------------------------
__global__ __launch_bounds__(256, 2)
void gemm_bf16(const ushort_t* __restrict__ A, int lda,
               const ushort_t* __restrict__ W, int ldw,
               const float* __restrict__ bias,
               void* __restrict__ Cout, int ldc, int K, int flags)
{
    __shared__ ushort_t sA[128 * 32];
    __shared__ ushort_t sB[128 * 32];
    const int m0 = blockIdx.y * 128;
    const int n0 = blockIdx.x * 128;
    const int t = threadIdx.x;
    const int wave = t >> 6;
    const int lane = t & 63;
    const int wm = (wave >> 1) * 64;
    const int wn = (wave & 1) * 64;

    floatx4 acc[4][4] = {};

    // staging addresses
    const int srow = wave * 32 + (lane >> 2);
    const int scol = (lane & 3) * 8;
    const ushort_t* gA0 = A + (long)(m0 + srow) * lda + scol;
    const ushort_t* gA1 = gA0 + (long)16 * lda;
    const ushort_t* gB0 = W + (long)(n0 + srow) * ldw + scol;
    const ushort_t* gB1 = gB0 + (long)16 * ldw;
    ushort_t* lA0 = sA + wave * 1024;
    ushort_t* lA1 = lA0 + 512;
    ushort_t* lB0 = sB + wave * 1024;
    ushort_t* lB1 = lB0 + 512;

    // fragment read addresses
    const int frow = lane & 15;
    const int fk = (lane >> 4) * 8;

    for (int kt = 0; kt < K; kt += 32) {
        async16(lA0, gA0); async16(lA1, gA1);
        async16(lB0, gB0); async16(lB1, gB1);
        gA0 += 32; gA1 += 32; gB0 += 32; gB1 += 32;
        __syncthreads();
        bf16x8 af[4], bfr[4];
#pragma unroll
        for (int i = 0; i < 4; i++)
            af[i] = *(const bf16x8*)(sA + (wm + i * 16 + frow) * 32 + fk);
#pragma unroll
        for (int j = 0; j < 4; j++)
            bfr[j] = *(const bf16x8*)(sB + (wn + j * 16 + frow) * 32 + fk);
#pragma unroll
        for (int i = 0; i < 4; i++)
#pragma unroll
            for (int j = 0; j < 4; j++)
                acc[i][j] = __builtin_amdgcn_mfma_f32_16x16x32_bf16(
                    af[i], bfr[j], acc[i][j], 0, 0, 0);
        __syncthreads();
    }

    // epilogue: row = m0+wm+i*16+quad*4+r, col = n0+wn+j*16+(lane&15)
    const int rbase = m0 + wm + (lane >> 4) * 4;
    const int cbase = n0 + wn + (lane & 15);
#pragma unroll
    for (int j = 0; j < 4; j++) {
        const int cc = cbase + j * 16;
        const float bv = (flags & 1) ? bias[cc] : 0.f;
#pragma unroll
        for (int i = 0; i < 4; i++) {
#pragma unroll
            for (int r = 0; r < 4; r++) {
                const int row = rbase + i * 16 + r;
                float v = acc[i][j][r] + bv;
                if (flags & 2) v = 0.5f * v * (1.0f + erff(v * 0.70710678118654752f));
                const long off = (long)row * ldc + cc;
                if (flags & 4)      ((float*)Cout)[off] += v;
                else if (flags & 8) ((ushort_t*)Cout)[off] = f2bf(v);
                else                ((float*)Cout)[off] = v;
            }
        }
    }
}

// ---------------------------------------------------------------------------
// fp32 NT GEMM (small shapes: proj/head). flags: 1=bias
// ---------------------------------------------------------------------------
__global__ void gemm_nt(const float* __restrict__ A, int lda,
                        const float* __restrict__ W, int ldw,
                        const float* __restrict__ bias,
                        float* __restrict__ C, int ldc,
                        int M, int Nout, int K, int flags)
{
    __shared__ float sA[16][65];
    __shared__ float sW[16][65];
    const int tx = threadIdx.x, ty = threadIdx.y;
    const int t = ty * 16 + tx;
    const int m0 = blockIdx.y * 64, n0 = blockIdx.x * 64;
    float acc[4][4] = {};

    for (int kt = 0; kt < K; kt += 16) {
#pragma unroll
        for (int s = 0; s < 4; s++) {
            int e = t + s * 256;
            int r = e >> 4, c = e & 15;
            int gm = m0 + r, gn = n0 + r, gk = kt + c;
            sA[c][r] = (gm < M) ? A[(long)gm * lda + gk] : 0.f;
            sW[c][r] = (gn < Nout) ? W[(long)gn * ldw + gk] : 0.f;
        }
        __syncthreads();
#pragma unroll
        for (int kk = 0; kk < 16; kk++) {
            float a[4], b[4];
#pragma unroll
            for (int i = 0; i < 4; i++) a[i] = sA[kk][ty + 16 * i];
#pragma unroll
            for (int j = 0; j < 4; j++) b[j] = sW[kk][tx + 16 * j];
#pragma unroll
            for (int i = 0; i < 4; i++)
#pragma unroll
                for (int j = 0; j < 4; j++)
                    acc[i][j] += a[i] * b[j];
        }
        __syncthreads();
    }
#pragma unroll
    for (int i = 0; i < 4; i++) {
        int m = m0 + ty + 16 * i;
        if (m >= M) continue;
#pragma unroll
        for (int j = 0; j < 4; j++) {
            int n = n0 + tx + 16 * j;
            if (n >= Nout) continue;
            float v = acc[i][j];
            if (flags & 1) v += bias[n];
            C[(long)m * ldc + n] = v;
        }
    }
}

// ---------------------------------------------------------------------------
// fp32 -> bf16 bulk convert (n % 4 == 0)
// ---------------------------------------------------------------------------
__global__ void f32_to_bf16(const float* __restrict__ in, ushort_t* __restrict__ out, long n)
{
    long i = ((long)blockIdx.x * 256 + threadIdx.x) * 4;
    if (i >= n) return;
    float4 v = *(const float4*)(in + i);
    ushort_t o0 = f2bf(v.x), o1 = f2bf(v.y), o2 = f2bf(v.z), o3 = f2bf(v.w);
    ushort4 o; o.x = o0; o.y = o1; o.z = o2; o.w = o3;
    *(ushort4*)(out + i) = o;
}

// ---------------------------------------------------------------------------
// LayerNorm over last dim (768), fp32 out. One block (256 threads) per row.
// ---------------------------------------------------------------------------
__global__ void layernorm_rows(const float* __restrict__ X,
                               const float* __restrict__ w,
                               const float* __restrict__ b,
                               float* __restrict__ Y)
{
    const int r = blockIdx.x;
    const int t = threadIdx.x;
    const float* xr = X + (long)r * DD;
    float x0 = xr[t], x1 = xr[t + 256], x2 = xr[t + 512];
    __shared__ float rs[256], rq[256];
    rs[t] = x0 + x1 + x2;
    rq[t] = x0 * x0 + x1 * x1 + x2 * x2;
    __syncthreads();
    for (int off = 128; off > 0; off >>= 1) {
        if (t < off) { rs[t] += rs[t + off]; rq[t] += rq[t + off]; }
        __syncthreads();
    }
    float mean = rs[0] * (1.f / 768.f);
    float var = rq[0] * (1.f / 768.f) - mean * mean;
    float rstd = rsqrtf(var + 1e-5f);
    float* yr = Y + (long)r * DD;
    yr[t]       = (x0 - mean) * rstd * w[t]       + b[t];
    yr[t + 256] = (x1 - mean) * rstd * w[t + 256] + b[t + 256];
    yr[t + 512] = (x2 - mean) * rstd * w[t + 512] + b[t + 512];
}

// LayerNorm, bf16 out.
__global__ void layernorm_rows_bf16(const float* __restrict__ X,
                                    const float* __restrict__ w,
                                    const float* __restrict__ b,
                                    ushort_t* __restrict__ Y)
{
    const int r = blockIdx.x;
    const int t = threadIdx.x;
    const float* xr = X + (long)r * DD;
    float x0 = xr[t], x1 = xr[t + 256], x2 = xr[t + 512];
    __shared__ float rs[256], rq[256];
    rs[t] = x0 + x1 + x2;
    rq[t] = x0 * x0 + x1 * x1 + x2 * x2;
    __syncthreads();
    for (int off = 128; off > 0; off >>= 1) {
        if (t < off) { rs[t] += rs[t + off]; rq[t] += rq[t + off]; }
        __syncthreads();
    }
    float mean = rs[0] * (1.f / 768.f);
    float var = rq[0] * (1.f / 768.f) - mean * mean;
    float rstd = rsqrtf(var + 1e-5f);
    ushort_t* yr = Y + (long)r * DD;
    yr[t]       = f2bf((x0 - mean) * rstd * w[t]       + b[t]);
    yr[t + 256] = f2bf((x1 - mean) * rstd * w[t + 256] + b[t + 256]);
    yr[t + 512] = f2bf((x2 - mean) * rstd * w[t + 512] + b[t + 512]);
}

// LayerNorm of cls rows only -> pooled (B,768) fp32
__global__ void ln_post_cls(const float* __restrict__ X,
                            const float* __restrict__ w,
                            const float* __restrict__ b,
                            float* __restrict__ pooled)
{
    const int bidx = blockIdx.x;   // batch
    const int t = threadIdx.x;
    const float* xr = X + (long)bidx * NTOK * DD;
    float x0 = xr[t], x1 = xr[t + 256], x2 = xr[t + 512];
    __shared__ float rs[256], rq[256];
    rs[t] = x0 + x1 + x2;
    rq[t] = x0 * x0 + x1 * x1 + x2 * x2;
    __syncthreads();
    for (int off = 128; off > 0; off >>= 1) {
        if (t < off) { rs[t] += rs[t + off]; rq[t] += rq[t + off]; }
        __syncthreads();
    }
    float mean = rs[0] * (1.f / 768.f);
    float var = rq[0] * (1.f / 768.f) - mean * mean;
    float rstd = rsqrtf(var + 1e-5f);
    float* yr = pooled + (long)bidx * DD;
    yr[t]       = (x0 - mean) * rstd * w[t]       + b[t];
    yr[t + 256] = (x1 - mean) * rstd * w[t + 256] + b[t + 256];
    yr[t + 512] = (x2 - mean) * rstd * w[t + 512] + b[t + 512];
}

// ---------------------------------------------------------------------------
// im2col -> bf16: x (B,C,224,224) -> patches (B*196, 768)
// ---------------------------------------------------------------------------
__global__ void im2col_bf16(const float* __restrict__ x, ushort_t* __restrict__ Pm)
{
    int idx = blockIdx.x * 256 + threadIdx.x;
    const int total = BB * NPATCH * DD;
    if (idx >= total) return;
    int row = idx / DD;
    int k = idx - row * DD;
    int b = row / NPATCH;
    int p = row - b * NPATCH;
    int py = p / 14, px = p - py * 14;
    int c = k >> 8;
    int rr = k & 255;
    int ph = rr >> 4, pw = rr & 15;
    Pm[idx] = f2bf(x[(((long)b * CC + c) * IMG + (py * 16 + ph)) * IMG + (px * 16 + pw)]);
}

// ---------------------------------------------------------------------------
// assemble: H[b,n,:] = (n==0 ? cls : patch_out[b,n-1,:]) + pos_embed[n,:]
// ---------------------------------------------------------------------------
__global__ void assemble_kernel(const float* __restrict__ tmp,
                                const float* __restrict__ cls,
                                const float* __restrict__ pos,
                                float* __restrict__ Hb)
{
    int idx = blockIdx.x * 256 + threadIdx.x;
    const int total = MTOK * DD;
    if (idx >= total) return;
    int row = idx / DD;
    int d = idx - row * DD;
    int b = row / NTOK;
    int n = row - b * NTOK;
    float v = (n == 0) ? cls[d] : tmp[((long)b * NPATCH + (n - 1)) * DD + d];
    Hb[idx] = v + pos[n * DD + d];
}

// ---------------------------------------------------------------------------
// attention scores: S[b,h,i,j] = 0.125 * sum_d Q[b,h,i,d]*K[b,h,j,d]
// QKV layout (token rows, 2304): Q at +h*64, K at +768+h*64, V at +1536+h*64
// ---------------------------------------------------------------------------
__global__ void attn_scores(const float* __restrict__ QKV, float* __restrict__ S)
{
    const int bh = blockIdx.z;
    const int b = bh / NH, h = bh - b * NH;
    const int i0 = blockIdx.y * 32, j0 = blockIdx.x * 32;
    __shared__ float sQ[32][65];
    __shared__ float sK[32][65];
    const int tx = threadIdx.x, ty = threadIdx.y;
    const int t = ty * 16 + tx;
    const float* Qb = QKV + (long)b * NTOK * 2304 + h * 64;
    const float* Kb = Qb + 768;
#pragma unroll
    for (int s = 0; s < 8; s++) {
        int e = t + s * 256;
        int row = e >> 6, col = e & 63;
        sQ[row][col] = (i0 + row < NTOK) ? Qb[(long)(i0 + row) * 2304 + col] : 0.f;
        sK[row][col] = (j0 + row < NTOK) ? Kb[(long)(j0 + row) * 2304 + col] : 0.f;
    }
    __syncthreads();
    float acc00 = 0.f, acc01 = 0.f, acc10 = 0.f, acc11 = 0.f;
#pragma unroll 8
    for (int k = 0; k < 64; k++) {
        float q0 = sQ[ty * 2][k], q1 = sQ[ty * 2 + 1][k];
        float k0 = sK[tx * 2][k], k1 = sK[tx * 2 + 1][k];
        acc00 += q0 * k0; acc01 += q0 * k1;
        acc10 += q1 * k0; acc11 += q1 * k1;
    }
    float* Sb = S + (long)bh * NTOK * NTOK;
    int i = i0 + ty * 2, j = j0 + tx * 2;
    const float sc = 0.125f;
    if (i < NTOK) {
        if (j < NTOK)     Sb[(long)i * NTOK + j]     = acc00 * sc;
        if (j + 1 < NTOK) Sb[(long)i * NTOK + j + 1] = acc01 * sc;
    }
    if (i + 1 < NTOK) {
        if (j < NTOK)     Sb[(long)(i + 1) * NTOK + j]     = acc10 * sc;
        if (j + 1 < NTOK) Sb[(long)(i + 1) * NTOK + j + 1] = acc11 * sc;
    }
}

// ---------------------------------------------------------------------------
// row softmax over 197 elements; one wave per row
// ---------------------------------------------------------------------------
__global__ void softmax197(float* __restrict__ S)
{
    const long row = blockIdx.x;
    const int lane = threadIdx.x;
    float* p = S + row * NTOK;
    float v[4];
    float m = -1e30f;
#pragma unroll
    for (int k = 0; k < 4; k++) {
        int j = lane + 64 * k;
        v[k] = (j < NTOK) ? p[j] : -1e30f;
        m = fmaxf(m, v[k]);
    }
    for (int off = 32; off > 0; off >>= 1) m = fmaxf(m, __shfl_xor(m, off));
    float s = 0.f;
#pragma unroll
    for (int k = 0; k < 4; k++) { v[k] = expf(v[k] - m); s += v[k]; }
    for (int off = 32; off > 0; off >>= 1) s += __shfl_xor(s, off);
    float inv = 1.f / s;
#pragma unroll
    for (int k = 0; k < 4; k++) {
        int j = lane + 64 * k;
        if (j < NTOK) p[j] = v[k] * inv;
    }
}

// ---------------------------------------------------------------------------
// O[b,n,h*64+d] = sum_j P[b,h,i,j] * V[b,h,j,d]  -> bf16 out
// ---------------------------------------------------------------------------
__global__ void attn_av(const float* __restrict__ S, const float* __restrict__ QKV,
                        ushort_t* __restrict__ O)
{
    const int bh = blockIdx.y;
    const int b = bh / NH, h = bh - b * NH;
    const int i0 = blockIdx.x * 4;
    const int tx = threadIdx.x, ty = threadIdx.y;
    const int t = ty * 64 + tx;
    __shared__ float sV[64][64];
    __shared__ float sS[4][64];
    const float* Vb = QKV + (long)b * NTOK * 2304 + 1536 + h * 64;
    const float* Sb = S + (long)bh * NTOK * NTOK;
    float acc = 0.f;
    for (int jc = 0; jc < 256; jc += 64) {
#pragma unroll
        for (int s = 0; s < 16; s++) {
            int e = t + s * 256;
            int row = e >> 6, col = e & 63;
            sV[row][col] = (jc + row < NTOK) ? Vb[(long)(jc + row) * 2304 + col] : 0.f;
        }
        {
            int row = t >> 6, col = t & 63;
            int i = i0 + row, j = jc + col;
            sS[row][col] = (i < NTOK && j < NTOK) ? Sb[(long)i * NTOK + j] : 0.f;
        }
        __syncthreads();
#pragma unroll 16
        for (int jj = 0; jj < 64; jj++)
            acc += sS[ty][jj] * sV[jj][tx];
        __syncthreads();
    }
    int i = i0 + ty;
    if (i < NTOK)
        O[((long)b * NTOK + i) * DD + h * 64 + tx] = f2bf(acc);
}

// ---------------------------------------------------------------------------
extern "C" void kernel_launch(void* const* d_in, const int* in_sizes, int n_in,
                              void* d_out, int out_size, void* d_ws, size_t ws_size,
                              hipStream_t stream)
{
    const float* x          = (const float*)d_in[0];
    const float* conv_w     = (const float*)d_in[1];
    const float* cls_token  = (const float*)d_in[2];
    const float* pos_embed  = (const float*)d_in[3];
    const float* ln_pre_w   = (const float*)d_in[4];
    const float* ln_pre_b   = (const float*)d_in[5];
    const float* ln1_w      = (const float*)d_in[6];
    const float* ln1_b      = (const float*)d_in[7];
    const float* qkv_w      = (const float*)d_in[8];
    const float* qkv_b      = (const float*)d_in[9];
    const float* attn_pw    = (const float*)d_in[10];
    const float* attn_pb    = (const float*)d_in[11];
    const float* ln2_w      = (const float*)d_in[12];
    const float* ln2_b      = (const float*)d_in[13];
    const float* fc_w       = (const float*)d_in[14];
    const float* fc_b       = (const float*)d_in[15];
    const float* cproj_w    = (const float*)d_in[16];
    const float* cproj_b    = (const float*)d_in[17];
    const float* ln_post_w  = (const float*)d_in[18];
    const float* ln_post_b  = (const float*)d_in[19];
    const float* proj_w     = (const float*)d_in[20];
    const float* head_w     = (const float*)d_in[21];
    const float* head_b     = (const float*)d_in[22];
    float* out = (float*)d_out;

    // -------- workspace layout (bytes) --------
    char* ws = (char*)d_ws;
    size_t off = 0;
    float*    X    = (float*)(ws + off);    off += (size_t)MPAD * DD * 4;      // 19.66 MB
    ushort_t* Hb   = (ushort_t*)(ws + off); off += (size_t)MPAD * DD * 2;      //  9.83 MB
    float*    BUF  = (float*)(ws + off);    off += (size_t)MPAD * 2304 * 4;    // 58.98 MB
    ushort_t* BUFb = (ushort_t*)(ws + off); off += (size_t)MPAD * MLPD * 2;    // 39.32 MB
    float*    Sc   = (float*)(ws + off);    off += (size_t)BB * NH * NTOK * NTOK * 4; // 59.61 MB
    ushort_t* Wb   = (ushort_t*)(ws + off); off += (size_t)85524480 * 2;       // 171.05 MB
    float*  pooled = (float*)(ws + off);    off += (size_t)BB * DD * 4;
    float*  z      = (float*)(ws + off);    off += (size_t)BB * PROJD * 4;

    // bf16 weight sub-buffers (element offsets)
    ushort_t* convb  = Wb;
    ushort_t* qkvb   = convb  + 589824;
    ushort_t* aprojb = qkvb   + 21233664;
    ushort_t* fcb    = aprojb + 7077888;
    ushort_t* cprojb = fcb    + 28311552;

    // -------- weight conversions (once per launch) --------
    {
        long n;
        n = 589824;   f32_to_bf16<<<(n / 4 + 255) / 256, 256, 0, stream>>>(conv_w,  convb,  n);
        n = 21233664; f32_to_bf16<<<(n / 4 + 255) / 256, 256, 0, stream>>>(qkv_w,   qkvb,   n);
        n = 7077888;  f32_to_bf16<<<(n / 4 + 255) / 256, 256, 0, stream>>>(attn_pw, aprojb, n);
        n = 28311552; f32_to_bf16<<<(n / 4 + 255) / 256, 256, 0, stream>>>(fc_w,    fcb,    n);
        n = 28311552; f32_to_bf16<<<(n / 4 + 255) / 256, 256, 0, stream>>>(cproj_w, cprojb, n);
    }

    // -------- patch embed --------
    {
        int tot = BB * NPATCH * DD;
        im2col_bf16<<<(tot + 255) / 256, 256, 0, stream>>>(x, BUFb);  // BUFb reused as im2col buf
        // patch GEMM: M=6272 (=49*128), N=768, K=768 -> Sc (fp32)
        gemm_bf16<<<dim3(DD / 128, 49), 256, 0, stream>>>(
            BUFb, DD, convb, DD, nullptr, Sc, DD, DD, 0);
        int tot2 = MTOK * DD;
        assemble_kernel<<<(tot2 + 255) / 256, 256, 0, stream>>>(Sc, cls_token, pos_embed, BUF); // BUF as fp32 temp
        layernorm_rows<<<MTOK, 256, 0, stream>>>(BUF, ln_pre_w, ln_pre_b, X);
    }

    // -------- transformer blocks --------
    for (int l = 0; l < NLAYER; l++) {
        layernorm_rows_bf16<<<MTOK, 256, 0, stream>>>(X, ln1_w + l * DD, ln1_b + l * DD, Hb);
        // qkv: M=MPAD, N=2304, K=768 -> BUF fp32 (+bias)
        gemm_bf16<<<dim3(2304 / 128, MPAD / 128), 256, 0, stream>>>(
            Hb, DD, qkvb + (long)l * 2304 * DD, DD, qkv_b + l * 2304,
            BUF, 2304, DD, 1);
        attn_scores<<<dim3(7, 7, BB * NH), dim3(16, 16), 0, stream>>>(BUF, Sc);
        softmax197<<<BB * NH * NTOK, 64, 0, stream>>>(Sc);
        attn_av<<<dim3((NTOK + 3) / 4, BB * NH), dim3(64, 4), 0, stream>>>(Sc, BUF, Hb);
        // attn_proj: M=MPAD, N=768, K=768 -> X fp32 accumulate (+bias)
        gemm_bf16<<<dim3(DD / 128, MPAD / 128), 256, 0, stream>>>(
            Hb, DD, aprojb + (long)l * DD * DD, DD, attn_pb + l * DD,
            X, DD, DD, 1 | 4);
        layernorm_rows_bf16<<<MTOK, 256, 0, stream>>>(X, ln2_w + l * DD, ln2_b + l * DD, Hb);
        // fc: M=MPAD, N=3072, K=768 -> BUFb bf16 (+bias, gelu)
        gemm_bf16<<<dim3(MLPD / 128, MPAD / 128), 256, 0, stream>>>(
            Hb, DD, fcb + (long)l * MLPD * DD, DD, fc_b + l * MLPD,
            BUFb, MLPD, DD, 1 | 2 | 8);
        // cproj: M=MPAD, N=768, K=3072 -> X fp32 accumulate (+bias)
        gemm_bf16<<<dim3(DD / 128, MPAD / 128), 256, 0, stream>>>(
            BUFb, MLPD, cprojb + (long)l * DD * MLPD, MLPD, cproj_b + l * DD,
            X, DD, MLPD, 1 | 4);
    }

    // -------- head --------
    ln_post_cls<<<BB, 256, 0, stream>>>(X, ln_post_w, ln_post_b, pooled);
    gemm_nt<<<dim3(PROJD / 64, 1), dim3(16, 16), 0, stream>>>(
        pooled, DD, proj_w, DD, nullptr, z, PROJD, BB, PROJD, DD, 0);
    gemm_nt<<<dim3((NCLS + 63) / 64, 1), dim3(16, 16), 0, stream>>>(
        z, PROJD, head_w, PROJD, head_b, out, NCLS, BB, NCLS, PROJD, 1);
}

// Round 3
// 5291.721 us; speedup vs baseline: 5.1426x; 1.4453x over previous
//
#include <hip/hip_runtime.h>
#include <math.h>
#include <stdint.h>

typedef unsigned short ushort_t;
typedef unsigned int uint_t;

// Problem constants
#define BB 32
#define CC 3
#define IMG 224
#define PP 16
#define DD 768
#define NTOK 197   // 196 patches + cls
#define NPATCH 196
#define NH 12
#define DHEAD 64
#define MLPD 3072
#define NLAYER 12
#define PROJD 512
#define NCLS 1000
#define MTOK (BB * NTOK)      // 6304
#define MPAD 6400             // padded to multiple of 128

typedef __bf16 bf16x8 __attribute__((ext_vector_type(8)));
typedef float floatx4 __attribute__((ext_vector_type(4)));

__device__ __forceinline__ ushort_t f2bf(float f) {
    union { float f; uint_t u; } x; x.f = f;
    uint_t r = x.u + 0x7fff + ((x.u >> 16) & 1);
    return (ushort_t)(r >> 16);
}

// CK-style async global->LDS direct copy, 16B per lane.
__device__ __forceinline__ void async16(void* lds, const void* g) {
    auto* gp = reinterpret_cast<const __attribute__((address_space(1))) uint_t*>(
        reinterpret_cast<uintptr_t>(g));
    auto* lp = reinterpret_cast<__attribute__((address_space(3))) uint_t*>(
        reinterpret_cast<uintptr_t>(lds));
    __builtin_amdgcn_global_load_lds(gp, lp, 16, 0, 0);
}

// ---------------------------------------------------------------------------
// bf16 MFMA NT GEMM: C[m,n] = sum_k A[m,k]*W[n,k]  (A,W bf16; C fp32 or bf16)
// Tile 128x128, K-step 32, 256 threads = 4 waves each computing 64x64.
// flags: 1 = +bias, 2 = exact gelu, 4 = fp32 accumulate into C, 8 = bf16 out
// ---------------------------------------------------------------------------
__global__ __launch_bounds__(256, 2)
void gemm_bf16(const ushort_t* __restrict__ A, int lda,
               const ushort_t* __restrict__ W, int ldw,
               const float* __restrict__ bias,
               void* __restrict__ Cout, int ldc, int K, int flags)
{
    __shared__ ushort_t sA[128 * 32];
    __shared__ ushort_t sB[128 * 32];
    const int m0 = blockIdx.y * 128;
    const int n0 = blockIdx.x * 128;
    const int t = threadIdx.x;
    const int wave = t >> 6;
    const int lane = t & 63;
    const int wm = (wave >> 1) * 64;
    const int wn = (wave & 1) * 64;

    floatx4 acc[4][4] = {};

    const int srow = wave * 32 + (lane >> 2);
    const int scol = (lane & 3) * 8;
    const ushort_t* gA0 = A + (long)(m0 + srow) * lda + scol;
    const ushort_t* gA1 = gA0 + (long)16 * lda;
    const ushort_t* gB0 = W + (long)(n0 + srow) * ldw + scol;
    const ushort_t* gB1 = gB0 + (long)16 * ldw;
    ushort_t* lA0 = sA + wave * 1024;
    ushort_t* lA1 = lA0 + 512;
    ushort_t* lB0 = sB + wave * 1024;
    ushort_t* lB1 = lB0 + 512;

    const int frow = lane & 15;
    const int fk = (lane >> 4) * 8;

    for (int kt = 0; kt < K; kt += 32) {
        async16(lA0, gA0); async16(lA1, gA1);
        async16(lB0, gB0); async16(lB1, gB1);
        gA0 += 32; gA1 += 32; gB0 += 32; gB1 += 32;
        __syncthreads();
        bf16x8 af[4], bfr[4];
#pragma unroll
        for (int i = 0; i < 4; i++)
            af[i] = *(const bf16x8*)(sA + (wm + i * 16 + frow) * 32 + fk);
#pragma unroll
        for (int j = 0; j < 4; j++)
            bfr[j] = *(const bf16x8*)(sB + (wn + j * 16 + frow) * 32 + fk);
#pragma unroll
        for (int i = 0; i < 4; i++)
#pragma unroll
            for (int j = 0; j < 4; j++)
                acc[i][j] = __builtin_amdgcn_mfma_f32_16x16x32_bf16(
                    af[i], bfr[j], acc[i][j], 0, 0, 0);
        __syncthreads();
    }

    const int rbase = m0 + wm + (lane >> 4) * 4;
    const int cbase = n0 + wn + (lane & 15);
#pragma unroll
    for (int j = 0; j < 4; j++) {
        const int cc = cbase + j * 16;
        const float bv = (flags & 1) ? bias[cc] : 0.f;
#pragma unroll
        for (int i = 0; i < 4; i++) {
#pragma unroll
            for (int r = 0; r < 4; r++) {
                const int row = rbase + i * 16 + r;
                float v = acc[i][j][r] + bv;
                if (flags & 2) v = 0.5f * v * (1.0f + erff(v * 0.70710678118654752f));
                const long off = (long)row * ldc + cc;
                if (flags & 4)      ((float*)Cout)[off] += v;
                else if (flags & 8) ((ushort_t*)Cout)[off] = f2bf(v);
                else                ((float*)Cout)[off] = v;
            }
        }
    }
}

// ---------------------------------------------------------------------------
// Fused attention: one block per (64-query tile, b*h). 4 waves, each 16 rows.
// QKV bf16 rows [token][2304]: Q +h*64, K +768+h*64, V +1536+h*64.
// S = Q K^T (MFMA, fp32 acc) -> softmax (shfl over 16-lane row groups)
// -> P bf16 via LDS -> O = P V (MFMA) -> bf16 out rows [token][768].
// ---------------------------------------------------------------------------
#define KP 224      // keys padded to 14*16
#define SK_ST 72    // sK row stride (elems): 144B, bank-uniform for b128
#define SV_ST 232   // sVt/sP row stride (elems): 464B, bank-uniform for b128

__global__ __launch_bounds__(256, 1)
void attn_fused(const ushort_t* __restrict__ QKV, ushort_t* __restrict__ O)
{
    __shared__ ushort_t sK[KP * SK_ST];        // [key][d]
    __shared__ ushort_t sVt[64 * SV_ST];       // [d][key] (transposed)
    __shared__ ushort_t sP[4][16 * SV_ST];     // per-wave P [m][key]

    const int bh = blockIdx.y;
    const int b = bh / NH, h = bh - b * NH;
    const int i0 = blockIdx.x * 64;
    const int t = threadIdx.x;
    const int wave = t >> 6, lane = t & 63;
    const int quad = lane >> 4, l16 = lane & 15;

    const ushort_t* base = QKV + (long)b * NTOK * 2304;

    // stage K: 16B per thread per pass, coalesced
    {
        const int key8 = t >> 3;
        const int d8 = (t & 7) * 8;
        const ushort_t* Kb = base + 768 + h * 64 + d8;
#pragma unroll
        for (int pass = 0; pass < 7; pass++) {
            int key = key8 + pass * 32;
            uint4 val = make_uint4(0, 0, 0, 0);
            if (key < NTOK) val = *(const uint4*)(Kb + (long)key * 2304);
            *(uint4*)(sK + key * SK_ST + d8) = val;
        }
    }
    // stage V transposed: scalar scatter (one-time cost)
    {
        const ushort_t* Vb = base + 1536 + h * 64;
        for (int idx = t; idx < KP * 64; idx += 256) {
            int key = idx >> 6;
            int d = idx & 63;
            ushort_t v = (key < NTOK) ? Vb[(long)key * 2304 + d] : (ushort_t)0;
            sVt[d * SV_ST + key] = v;
        }
    }
    // Q fragments directly from global (A-layout: m=l16, k=quad*8+j)
    int qrow = i0 + wave * 16 + l16;
    int qr_c = (qrow < NTOK) ? qrow : (NTOK - 1);
    const ushort_t* Qb = base + h * 64;
    bf16x8 aq0 = *(const bf16x8*)(Qb + (long)qr_c * 2304 + quad * 8);
    bf16x8 aq1 = *(const bf16x8*)(Qb + (long)qr_c * 2304 + 32 + quad * 8);

    __syncthreads();

    // ---- S = Q K^T : 14 key tiles x 2 k-steps
    floatx4 sacc[14];
#pragma unroll
    for (int i = 0; i < 14; i++) sacc[i] = (floatx4){0.f, 0.f, 0.f, 0.f};
#pragma unroll
    for (int tile = 0; tile < 14; tile++) {
        const ushort_t* kp = sK + (tile * 16 + l16) * SK_ST + quad * 8;
        bf16x8 b0 = *(const bf16x8*)(kp);
        bf16x8 b1 = *(const bf16x8*)(kp + 32);
        sacc[tile] = __builtin_amdgcn_mfma_f32_16x16x32_bf16(aq0, b0, sacc[tile], 0, 0, 0);
        sacc[tile] = __builtin_amdgcn_mfma_f32_16x16x32_bf16(aq1, b1, sacc[tile], 0, 0, 0);
    }

    // ---- softmax: row = quad*4 + r; the 16 lanes sharing `quad` hold a row
    const float scale = 0.125f;
    float mrow[4], lrow[4];
#pragma unroll
    for (int r = 0; r < 4; r++) mrow[r] = -1e30f;
#pragma unroll
    for (int tile = 0; tile < 14; tile++) {
        int col = tile * 16 + l16;
        bool valid = (col < NTOK);
#pragma unroll
        for (int r = 0; r < 4; r++) {
            float s = valid ? sacc[tile][r] * scale : -1e30f;
            sacc[tile][r] = s;
            mrow[r] = fmaxf(mrow[r], s);
        }
    }
#pragma unroll
    for (int r = 0; r < 4; r++) {
        for (int m = 1; m < 16; m <<= 1)
            mrow[r] = fmaxf(mrow[r], __shfl_xor(mrow[r], m));
        lrow[r] = 0.f;
    }
#pragma unroll
    for (int tile = 0; tile < 14; tile++) {
#pragma unroll
        for (int r = 0; r < 4; r++) {
            float p = expf(sacc[tile][r] - mrow[r]);
            sacc[tile][r] = p;
            lrow[r] += p;
        }
    }
#pragma unroll
    for (int r = 0; r < 4; r++) {
        for (int m = 1; m < 16; m <<= 1)
            lrow[r] += __shfl_xor(lrow[r], m);
        lrow[r] = 1.f / lrow[r];
    }
    // write normalized P (bf16) to per-wave LDS, [m][key]
    ushort_t* sp = sP[wave];
#pragma unroll
    for (int tile = 0; tile < 14; tile++) {
        int col = tile * 16 + l16;
#pragma unroll
        for (int r = 0; r < 4; r++)
            sp[(quad * 4 + r) * SV_ST + col] = f2bf(sacc[tile][r] * lrow[r]);
    }
    __syncthreads();

    // ---- O = P V : A = sP[wave], B = sVt; 7 k-steps of 32 keys
    floatx4 oacc[4];
#pragma unroll
    for (int i = 0; i < 4; i++) oacc[i] = (floatx4){0.f, 0.f, 0.f, 0.f};
#pragma unroll
    for (int ks = 0; ks < 7; ks++) {
        bf16x8 ap = *(const bf16x8*)(sp + l16 * SV_ST + ks * 32 + quad * 8);
#pragma unroll
        for (int nt = 0; nt < 4; nt++) {
            bf16x8 bv = *(const bf16x8*)(sVt + (nt * 16 + l16) * SV_ST + ks * 32 + quad * 8);
            oacc[nt] = __builtin_amdgcn_mfma_f32_16x16x32_bf16(ap, bv, oacc[nt], 0, 0, 0);
        }
    }
    // ---- write O (bf16) into token-major [197*b + row][768]
    int orow0 = i0 + wave * 16 + quad * 4;
#pragma unroll
    for (int nt = 0; nt < 4; nt++) {
        int col = h * 64 + nt * 16 + l16;
#pragma unroll
        for (int r = 0; r < 4; r++) {
            int row = orow0 + r;
            if (row < NTOK)
                O[((long)b * NTOK + row) * DD + col] = f2bf(oacc[nt][r]);
        }
    }
}

// ---------------------------------------------------------------------------
// fp32 NT GEMM (small shapes: proj/head). flags: 1=bias
// ---------------------------------------------------------------------------
__global__ void gemm_nt(const float* __restrict__ A, int lda,
                        const float* __restrict__ W, int ldw,
                        const float* __restrict__ bias,
                        float* __restrict__ C, int ldc,
                        int M, int Nout, int K, int flags)
{
    __shared__ float sA[16][65];
    __shared__ float sW[16][65];
    const int tx = threadIdx.x, ty = threadIdx.y;
    const int t = ty * 16 + tx;
    const int m0 = blockIdx.y * 64, n0 = blockIdx.x * 64;
    float acc[4][4] = {};

    for (int kt = 0; kt < K; kt += 16) {
#pragma unroll
        for (int s = 0; s < 4; s++) {
            int e = t + s * 256;
            int r = e >> 4, c = e & 15;
            int gm = m0 + r, gn = n0 + r, gk = kt + c;
            sA[c][r] = (gm < M) ? A[(long)gm * lda + gk] : 0.f;
            sW[c][r] = (gn < Nout) ? W[(long)gn * ldw + gk] : 0.f;
        }
        __syncthreads();
#pragma unroll
        for (int kk = 0; kk < 16; kk++) {
            float a[4], b[4];
#pragma unroll
            for (int i = 0; i < 4; i++) a[i] = sA[kk][ty + 16 * i];
#pragma unroll
            for (int j = 0; j < 4; j++) b[j] = sW[kk][tx + 16 * j];
#pragma unroll
            for (int i = 0; i < 4; i++)
#pragma unroll
                for (int j = 0; j < 4; j++)
                    acc[i][j] += a[i] * b[j];
        }
        __syncthreads();
    }
#pragma unroll
    for (int i = 0; i < 4; i++) {
        int m = m0 + ty + 16 * i;
        if (m >= M) continue;
#pragma unroll
        for (int j = 0; j < 4; j++) {
            int n = n0 + tx + 16 * j;
            if (n >= Nout) continue;
            float v = acc[i][j];
            if (flags & 1) v += bias[n];
            C[(long)m * ldc + n] = v;
        }
    }
}

// ---------------------------------------------------------------------------
// fp32 -> bf16 bulk convert (n % 4 == 0)
// ---------------------------------------------------------------------------
__global__ void f32_to_bf16(const float* __restrict__ in, ushort_t* __restrict__ out, long n)
{
    long i = ((long)blockIdx.x * 256 + threadIdx.x) * 4;
    if (i >= n) return;
    float4 v = *(const float4*)(in + i);
    ushort4 o;
    o.x = f2bf(v.x); o.y = f2bf(v.y); o.z = f2bf(v.z); o.w = f2bf(v.w);
    *(ushort4*)(out + i) = o;
}

// ---------------------------------------------------------------------------
// LayerNorm over last dim (768), fp32 out.
// ---------------------------------------------------------------------------
__global__ void layernorm_rows(const float* __restrict__ X,
                               const float* __restrict__ w,
                               const float* __restrict__ b,
                               float* __restrict__ Y)
{
    const int r = blockIdx.x;
    const int t = threadIdx.x;
    const float* xr = X + (long)r * DD;
    float x0 = xr[t], x1 = xr[t + 256], x2 = xr[t + 512];
    __shared__ float rs[256], rq[256];
    rs[t] = x0 + x1 + x2;
    rq[t] = x0 * x0 + x1 * x1 + x2 * x2;
    __syncthreads();
    for (int off = 128; off > 0; off >>= 1) {
        if (t < off) { rs[t] += rs[t + off]; rq[t] += rq[t + off]; }
        __syncthreads();
    }
    float mean = rs[0] * (1.f / 768.f);
    float var = rq[0] * (1.f / 768.f) - mean * mean;
    float rstd = rsqrtf(var + 1e-5f);
    float* yr = Y + (long)r * DD;
    yr[t]       = (x0 - mean) * rstd * w[t]       + b[t];
    yr[t + 256] = (x1 - mean) * rstd * w[t + 256] + b[t + 256];
    yr[t + 512] = (x2 - mean) * rstd * w[t + 512] + b[t + 512];
}

// LayerNorm, bf16 out.
__global__ void layernorm_rows_bf16(const float* __restrict__ X,
                                    const float* __restrict__ w,
                                    const float* __restrict__ b,
                                    ushort_t* __restrict__ Y)
{
    const int r = blockIdx.x;
    const int t = threadIdx.x;
    const float* xr = X + (long)r * DD;
    float x0 = xr[t], x1 = xr[t + 256], x2 = xr[t + 512];
    __shared__ float rs[256], rq[256];
    rs[t] = x0 + x1 + x2;
    rq[t] = x0 * x0 + x1 * x1 + x2 * x2;
    __syncthreads();
    for (int off = 128; off > 0; off >>= 1) {
        if (t < off) { rs[t] += rs[t + off]; rq[t] += rq[t + off]; }
        __syncthreads();
    }
    float mean = rs[0] * (1.f / 768.f);
    float var = rq[0] * (1.f / 768.f) - mean * mean;
    float rstd = rsqrtf(var + 1e-5f);
    ushort_t* yr = Y + (long)r * DD;
    yr[t]       = f2bf((x0 - mean) * rstd * w[t]       + b[t]);
    yr[t + 256] = f2bf((x1 - mean) * rstd * w[t + 256] + b[t + 256]);
    yr[t + 512] = f2bf((x2 - mean) * rstd * w[t + 512] + b[t + 512]);
}

// LayerNorm of cls rows only -> pooled (B,768) fp32
__global__ void ln_post_cls(const float* __restrict__ X,
                            const float* __restrict__ w,
                            const float* __restrict__ b,
                            float* __restrict__ pooled)
{
    const int bidx = blockIdx.x;
    const int t = threadIdx.x;
    const float* xr = X + (long)bidx * NTOK * DD;
    float x0 = xr[t], x1 = xr[t + 256], x2 = xr[t + 512];
    __shared__ float rs[256], rq[256];
    rs[t] = x0 + x1 + x2;
    rq[t] = x0 * x0 + x1 * x1 + x2 * x2;
    __syncthreads();
    for (int off = 128; off > 0; off >>= 1) {
        if (t < off) { rs[t] += rs[t + off]; rq[t] += rq[t + off]; }
        __syncthreads();
    }
    float mean = rs[0] * (1.f / 768.f);
    float var = rq[0] * (1.f / 768.f) - mean * mean;
    float rstd = rsqrtf(var + 1e-5f);
    float* yr = pooled + (long)bidx * DD;
    yr[t]       = (x0 - mean) * rstd * w[t]       + b[t];
    yr[t + 256] = (x1 - mean) * rstd * w[t + 256] + b[t + 256];
    yr[t + 512] = (x2 - mean) * rstd * w[t + 512] + b[t + 512];
}

// ---------------------------------------------------------------------------
// im2col -> bf16: x (B,C,224,224) -> patches (B*196, 768)
// ---------------------------------------------------------------------------
__global__ void im2col_bf16(const float* __restrict__ x, ushort_t* __restrict__ Pm)
{
    int idx = blockIdx.x * 256 + threadIdx.x;
    const int total = BB * NPATCH * DD;
    if (idx >= total) return;
    int row = idx / DD;
    int k = idx - row * DD;
    int b = row / NPATCH;
    int p = row - b * NPATCH;
    int py = p / 14, px = p - py * 14;
    int c = k >> 8;
    int rr = k & 255;
    int ph = rr >> 4, pw = rr & 15;
    Pm[idx] = f2bf(x[(((long)b * CC + c) * IMG + (py * 16 + ph)) * IMG + (px * 16 + pw)]);
}

// ---------------------------------------------------------------------------
// assemble: Tmp[b,n,:] = (n==0 ? cls : patch_out[b,n-1,:]) + pos_embed[n,:]
// ---------------------------------------------------------------------------
__global__ void assemble_kernel(const float* __restrict__ tmp,
                                const float* __restrict__ cls,
                                const float* __restrict__ pos,
                                float* __restrict__ Hb)
{
    int idx = blockIdx.x * 256 + threadIdx.x;
    const int total = MTOK * DD;
    if (idx >= total) return;
    int row = idx / DD;
    int d = idx - row * DD;
    int b = row / NTOK;
    int n = row - b * NTOK;
    float v = (n == 0) ? cls[d] : tmp[((long)b * NPATCH + (n - 1)) * DD + d];
    Hb[idx] = v + pos[n * DD + d];
}

// ---------------------------------------------------------------------------
extern "C" void kernel_launch(void* const* d_in, const int* in_sizes, int n_in,
                              void* d_out, int out_size, void* d_ws, size_t ws_size,
                              hipStream_t stream)
{
    const float* x          = (const float*)d_in[0];
    const float* conv_w     = (const float*)d_in[1];
    const float* cls_token  = (const float*)d_in[2];
    const float* pos_embed  = (const float*)d_in[3];
    const float* ln_pre_w   = (const float*)d_in[4];
    const float* ln_pre_b   = (const float*)d_in[5];
    const float* ln1_w      = (const float*)d_in[6];
    const float* ln1_b      = (const float*)d_in[7];
    const float* qkv_w      = (const float*)d_in[8];
    const float* qkv_b      = (const float*)d_in[9];
    const float* attn_pw    = (const float*)d_in[10];
    const float* attn_pb    = (const float*)d_in[11];
    const float* ln2_w      = (const float*)d_in[12];
    const float* ln2_b      = (const float*)d_in[13];
    const float* fc_w       = (const float*)d_in[14];
    const float* fc_b       = (const float*)d_in[15];
    const float* cproj_w    = (const float*)d_in[16];
    const float* cproj_b    = (const float*)d_in[17];
    const float* ln_post_w  = (const float*)d_in[18];
    const float* ln_post_b  = (const float*)d_in[19];
    const float* proj_w     = (const float*)d_in[20];
    const float* head_w     = (const float*)d_in[21];
    const float* head_b     = (const float*)d_in[22];
    float* out = (float*)d_out;

    // -------- workspace layout --------
    char* ws = (char*)d_ws;
    size_t off = 0;
    float*    X     = (float*)(ws + off);    off += (size_t)MPAD * DD * 4;        // residual (fp32)
    ushort_t* Hb    = (ushort_t*)(ws + off); off += (size_t)MPAD * DD * 2;        // bf16 activations
    ushort_t* QKVb  = (ushort_t*)(ws + off); off += (size_t)MPAD * 2304 * 2;      // bf16 qkv
    ushort_t* Hmlp  = (ushort_t*)(ws + off); off += (size_t)MPAD * MLPD * 2;      // bf16 mlp / im2col
    float*    ScF   = (float*)(ws + off);    off += (size_t)(BB * NPATCH) * DD * 4; // patch gemm out
    float*    TmpF  = (float*)(ws + off);    off += (size_t)MPAD * DD * 4;        // assemble out
    ushort_t* Wb    = (ushort_t*)(ws + off); off += (size_t)85524480 * 2;         // bf16 weights
    float*  pooled  = (float*)(ws + off);    off += (size_t)BB * DD * 4;
    float*  z       = (float*)(ws + off);    off += (size_t)BB * PROJD * 4;

    ushort_t* convb  = Wb;
    ushort_t* qkvb   = convb  + 589824;
    ushort_t* aprojb = qkvb   + 21233664;
    ushort_t* fcb    = aprojb + 7077888;
    ushort_t* cprojb = fcb    + 28311552;

    // -------- weight conversions --------
    {
        long n;
        n = 589824;   f32_to_bf16<<<(n / 4 + 255) / 256, 256, 0, stream>>>(conv_w,  convb,  n);
        n = 21233664; f32_to_bf16<<<(n / 4 + 255) / 256, 256, 0, stream>>>(qkv_w,   qkvb,   n);
        n = 7077888;  f32_to_bf16<<<(n / 4 + 255) / 256, 256, 0, stream>>>(attn_pw, aprojb, n);
        n = 28311552; f32_to_bf16<<<(n / 4 + 255) / 256, 256, 0, stream>>>(fc_w,    fcb,    n);
        n = 28311552; f32_to_bf16<<<(n / 4 + 255) / 256, 256, 0, stream>>>(cproj_w, cprojb, n);
    }

    // -------- patch embed --------
    {
        int tot = BB * NPATCH * DD;
        im2col_bf16<<<(tot + 255) / 256, 256, 0, stream>>>(x, Hmlp);
        gemm_bf16<<<dim3(DD / 128, 49), 256, 0, stream>>>(
            Hmlp, DD, convb, DD, nullptr, ScF, DD, DD, 0);
        int tot2 = MTOK * DD;
        assemble_kernel<<<(tot2 + 255) / 256, 256, 0, stream>>>(ScF, cls_token, pos_embed, TmpF);
        layernorm_rows<<<MTOK, 256, 0, stream>>>(TmpF, ln_pre_w, ln_pre_b, X);
    }

    // -------- transformer blocks --------
    for (int l = 0; l < NLAYER; l++) {
        layernorm_rows_bf16<<<MTOK, 256, 0, stream>>>(X, ln1_w + l * DD, ln1_b + l * DD, Hb);
        gemm_bf16<<<dim3(2304 / 128, MPAD / 128), 256, 0, stream>>>(
            Hb, DD, qkvb + (long)l * 2304 * DD, DD, qkv_b + l * 2304,
            QKVb, 2304, DD, 1 | 8);
        attn_fused<<<dim3(4, BB * NH), 256, 0, stream>>>(QKVb, Hb);
        gemm_bf16<<<dim3(DD / 128, MPAD / 128), 256, 0, stream>>>(
            Hb, DD, aprojb + (long)l * DD * DD, DD, attn_pb + l * DD,
            X, DD, DD, 1 | 4);
        layernorm_rows_bf16<<<MTOK, 256, 0, stream>>>(X, ln2_w + l * DD, ln2_b + l * DD, Hb);
        gemm_bf16<<<dim3(MLPD / 128, MPAD / 128), 256, 0, stream>>>(
            Hb, DD, fcb + (long)l * MLPD * DD, DD, fc_b + l * MLPD,
            Hmlp, MLPD, DD, 1 | 2 | 8);
        gemm_bf16<<<dim3(DD / 128, MPAD / 128), 256, 0, stream>>>(
            Hmlp, MLPD, cprojb + (long)l * DD * MLPD, MLPD, cproj_b + l * DD,
            X, DD, MLPD, 1 | 4);
    }

    // -------- head --------
    ln_post_cls<<<BB, 256, 0, stream>>>(X, ln_post_w, ln_post_b, pooled);
    gemm_nt<<<dim3(PROJD / 64, 1), dim3(16, 16), 0, stream>>>(
        pooled, DD, proj_w, DD, nullptr, z, PROJD, BB, PROJD, DD, 0);
    gemm_nt<<<dim3((NCLS + 63) / 64, 1), dim3(16, 16), 0, stream>>>(
        z, PROJD, head_w, PROJD, head_b, out, NCLS, BB, NCLS, PROJD, 1);
}

// Round 4
// 3797.636 us; speedup vs baseline: 7.1659x; 1.3934x over previous
//
#include <hip/hip_runtime.h>
#include <math.h>
#include <stdint.h>

typedef unsigned short ushort_t;
typedef unsigned int uint_t;

// Problem constants
#define BB 32
#define CC 3
#define IMG 224
#define PP 16
#define DD 768
#define NTOK 197   // 196 patches + cls
#define NPATCH 196
#define NH 12
#define DHEAD 64
#define MLPD 3072
#define NLAYER 12
#define PROJD 512
#define NCLS 1000
#define MTOK (BB * NTOK)      // 6304
#define MPAD 6400             // padded to multiple of 128

typedef __bf16 bf16x8 __attribute__((ext_vector_type(8)));
typedef float floatx4 __attribute__((ext_vector_type(4)));

__device__ __forceinline__ ushort_t f2bf(float f) {
    union { float f; uint_t u; } x; x.f = f;
    uint_t r = x.u + 0x7fff + ((x.u >> 16) & 1);
    return (ushort_t)(r >> 16);
}

// CK-style async global->LDS direct copy, 16B per lane.
// NOTE: LDS dest is wave-uniform base + lane*16B.
__device__ __forceinline__ void async16(void* lds, const void* g) {
    auto* gp = reinterpret_cast<const __attribute__((address_space(1))) uint_t*>(
        reinterpret_cast<uintptr_t>(g));
    auto* lp = reinterpret_cast<__attribute__((address_space(3))) uint_t*>(
        reinterpret_cast<uintptr_t>(lds));
    __builtin_amdgcn_global_load_lds(gp, lp, 16, 0, 0);
}

// ---------------------------------------------------------------------------
// bf16 MFMA NT GEMM: C[m,n] = sum_k A[m,k]*W[n,k]  (A,W bf16; C fp32 or bf16)
// Tile 128x128, K-step 32, 256 threads = 4 waves each computing 64x64.
// flags: 1 = +bias, 2 = exact gelu, 4 = fp32 accumulate into C, 8 = bf16 out
// ---------------------------------------------------------------------------
__global__ __launch_bounds__(256, 2)
void gemm_bf16(const ushort_t* __restrict__ A, int lda,
               const ushort_t* __restrict__ W, int ldw,
               const float* __restrict__ bias,
               void* __restrict__ Cout, int ldc, int K, int flags)
{
    __shared__ ushort_t sA[128 * 32];
    __shared__ ushort_t sB[128 * 32];
    const int m0 = blockIdx.y * 128;
    const int n0 = blockIdx.x * 128;
    const int t = threadIdx.x;
    const int wave = t >> 6;
    const int lane = t & 63;
    const int wm = (wave >> 1) * 64;
    const int wn = (wave & 1) * 64;

    floatx4 acc[4][4] = {};

    const int srow = wave * 32 + (lane >> 2);
    const int scol = (lane & 3) * 8;
    const ushort_t* gA0 = A + (long)(m0 + srow) * lda + scol;
    const ushort_t* gA1 = gA0 + (long)16 * lda;
    const ushort_t* gB0 = W + (long)(n0 + srow) * ldw + scol;
    const ushort_t* gB1 = gB0 + (long)16 * ldw;
    ushort_t* lA0 = sA + wave * 1024;
    ushort_t* lA1 = lA0 + 512;
    ushort_t* lB0 = sB + wave * 1024;
    ushort_t* lB1 = lB0 + 512;

    const int frow = lane & 15;
    const int fk = (lane >> 4) * 8;

    for (int kt = 0; kt < K; kt += 32) {
        async16(lA0, gA0); async16(lA1, gA1);
        async16(lB0, gB0); async16(lB1, gB1);
        gA0 += 32; gA1 += 32; gB0 += 32; gB1 += 32;
        __syncthreads();
        bf16x8 af[4], bfr[4];
#pragma unroll
        for (int i = 0; i < 4; i++)
            af[i] = *(const bf16x8*)(sA + (wm + i * 16 + frow) * 32 + fk);
#pragma unroll
        for (int j = 0; j < 4; j++)
            bfr[j] = *(const bf16x8*)(sB + (wn + j * 16 + frow) * 32 + fk);
#pragma unroll
        for (int i = 0; i < 4; i++)
#pragma unroll
            for (int j = 0; j < 4; j++)
                acc[i][j] = __builtin_amdgcn_mfma_f32_16x16x32_bf16(
                    af[i], bfr[j], acc[i][j], 0, 0, 0);
        __syncthreads();
    }

    const int rbase = m0 + wm + (lane >> 4) * 4;
    const int cbase = n0 + wn + (lane & 15);
#pragma unroll
    for (int j = 0; j < 4; j++) {
        const int cc = cbase + j * 16;
        const float bv = (flags & 1) ? bias[cc] : 0.f;
#pragma unroll
        for (int i = 0; i < 4; i++) {
#pragma unroll
            for (int r = 0; r < 4; r++) {
                const int row = rbase + i * 16 + r;
                float v = acc[i][j][r] + bv;
                if (flags & 2) v = 0.5f * v * (1.0f + erff(v * 0.70710678118654752f));
                const long off = (long)row * ldc + cc;
                if (flags & 4)      ((float*)Cout)[off] += v;
                else if (flags & 8) ((ushort_t*)Cout)[off] = f2bf(v);
                else                ((float*)Cout)[off] = v;
            }
        }
    }
}

// ---------------------------------------------------------------------------
// bf16 MFMA NT GEMM, tile 128x64 (for N=768 GEMMs: doubles grid vs 128x128).
// 4 waves, each computing 32x64. Same flags.
// ---------------------------------------------------------------------------
__global__ __launch_bounds__(256, 2)
void gemm_bf16_n64(const ushort_t* __restrict__ A, int lda,
                   const ushort_t* __restrict__ W, int ldw,
                   const float* __restrict__ bias,
                   void* __restrict__ Cout, int ldc, int K, int flags)
{
    __shared__ ushort_t sA[128 * 32];
    __shared__ ushort_t sB[64 * 32];
    const int m0 = blockIdx.y * 128;
    const int n0 = blockIdx.x * 64;
    const int t = threadIdx.x;
    const int wave = t >> 6;
    const int lane = t & 63;
    const int wm = wave * 32;

    floatx4 acc[2][4] = {};

    const int srowA = wave * 32 + (lane >> 2);
    const int srowB = wave * 16 + (lane >> 2);
    const int scol = (lane & 3) * 8;
    const ushort_t* gA0 = A + (long)(m0 + srowA) * lda + scol;
    const ushort_t* gA1 = gA0 + (long)16 * lda;
    const ushort_t* gB0 = W + (long)(n0 + srowB) * ldw + scol;
    ushort_t* lA0 = sA + wave * 1024;
    ushort_t* lA1 = lA0 + 512;
    ushort_t* lB0 = sB + wave * 512;

    const int frow = lane & 15;
    const int fk = (lane >> 4) * 8;

    for (int kt = 0; kt < K; kt += 32) {
        async16(lA0, gA0); async16(lA1, gA1);
        async16(lB0, gB0);
        gA0 += 32; gA1 += 32; gB0 += 32;
        __syncthreads();
        bf16x8 af[2], bfr[4];
#pragma unroll
        for (int i = 0; i < 2; i++)
            af[i] = *(const bf16x8*)(sA + (wm + i * 16 + frow) * 32 + fk);
#pragma unroll
        for (int j = 0; j < 4; j++)
            bfr[j] = *(const bf16x8*)(sB + (j * 16 + frow) * 32 + fk);
#pragma unroll
        for (int i = 0; i < 2; i++)
#pragma unroll
            for (int j = 0; j < 4; j++)
                acc[i][j] = __builtin_amdgcn_mfma_f32_16x16x32_bf16(
                    af[i], bfr[j], acc[i][j], 0, 0, 0);
        __syncthreads();
    }

    const int rbase = m0 + wm + (lane >> 4) * 4;
    const int cbase = n0 + (lane & 15);
#pragma unroll
    for (int j = 0; j < 4; j++) {
        const int cc = cbase + j * 16;
        const float bv = (flags & 1) ? bias[cc] : 0.f;
#pragma unroll
        for (int i = 0; i < 2; i++) {
#pragma unroll
            for (int r = 0; r < 4; r++) {
                const int row = rbase + i * 16 + r;
                float v = acc[i][j][r] + bv;
                if (flags & 2) v = 0.5f * v * (1.0f + erff(v * 0.70710678118654752f));
                const long off = (long)row * ldc + cc;
                if (flags & 4)      ((float*)Cout)[off] += v;
                else if (flags & 8) ((ushort_t*)Cout)[off] = f2bf(v);
                else                ((float*)Cout)[off] = v;
            }
        }
    }
}

// ---------------------------------------------------------------------------
// Fused attention. One block per (64-query tile, b*h); 4 waves x 16 rows.
// LDS: sKP holds K [224][72] during S-phase, then (aliased) per-wave P;
// sVt holds V transposed [d][key] with +8-elem skew per 8 d-rows so the
// transpose scatter is bank-conflict-free. Total 62 KB -> 2 blocks/CU.
// ---------------------------------------------------------------------------
#define KP 224      // keys padded to 14*16
#define SK_ST 72    // sK row stride (elems)
#define SV_ST 232   // base row stride (elems) for sVt / sP (+skew)

__device__ __forceinline__ int vt_row(int d) { return d * SV_ST + (d >> 3) * 8; }

__global__ __launch_bounds__(256, 2)
void attn_fused(const ushort_t* __restrict__ QKV, ushort_t* __restrict__ O)
{
    __shared__ ushort_t sKP[KP * SK_ST];            // 32,256 B (aliased by P)
    __shared__ ushort_t sVt[64 * SV_ST + 64];       // 29,952 B

    const int bh = blockIdx.y;
    const int b = bh / NH, h = bh - b * NH;
    const int i0 = blockIdx.x * 64;
    const int t = threadIdx.x;
    const int wave = t >> 6, lane = t & 63;
    const int quad = lane >> 4, l16 = lane & 15;

    const ushort_t* base = QKV + (long)b * NTOK * 2304;

    // ---- stage K [key][d]: uint4 per lane, coalesced
    {
        const int key8 = t >> 3;
        const int d8 = (t & 7) * 8;
        const ushort_t* Kb = base + 768 + h * 64 + d8;
#pragma unroll
        for (int pass = 0; pass < 7; pass++) {
            int key = key8 + pass * 32;
            uint4 val = make_uint4(0, 0, 0, 0);
            if (key < NTOK) val = *(const uint4*)(Kb + (long)key * 2304);
            *(uint4*)(sKP + key * SK_ST + d8) = val;
        }
    }
    // ---- stage V transposed: uint4 global read + 8 skewed b16 scatters
    {
        const int key8 = t >> 3;
        const int d8 = (t & 7) * 8;
        const ushort_t* Vb = base + 1536 + h * 64 + d8;
#pragma unroll
        for (int pass = 0; pass < 7; pass++) {
            int key = key8 + pass * 32;
            union { uint4 v; ushort_t u[8]; } val;
            val.v = make_uint4(0, 0, 0, 0);
            if (key < NTOK) val.v = *(const uint4*)(Vb + (long)key * 2304);
#pragma unroll
            for (int i = 0; i < 8; i++)
                sVt[vt_row(d8 + i) + key] = val.u[i];
        }
    }
    // ---- Q fragments from global (A-layout: m=l16, k=quad*8+j)
    int qrow = i0 + wave * 16 + l16;
    int qr_c = (qrow < NTOK) ? qrow : (NTOK - 1);
    const ushort_t* Qb = base + h * 64;
    bf16x8 aq0 = *(const bf16x8*)(Qb + (long)qr_c * 2304 + quad * 8);
    bf16x8 aq1 = *(const bf16x8*)(Qb + (long)qr_c * 2304 + 32 + quad * 8);

    __syncthreads();

    // ---- S = Q K^T : 14 key tiles x 2 k-steps
    floatx4 sacc[14];
#pragma unroll
    for (int i = 0; i < 14; i++) sacc[i] = (floatx4){0.f, 0.f, 0.f, 0.f};
#pragma unroll
    for (int tile = 0; tile < 14; tile++) {
        const ushort_t* kp = sKP + (tile * 16 + l16) * SK_ST + quad * 8;
        bf16x8 b0 = *(const bf16x8*)(kp);
        bf16x8 b1 = *(const bf16x8*)(kp + 32);
        sacc[tile] = __builtin_amdgcn_mfma_f32_16x16x32_bf16(aq0, b0, sacc[tile], 0, 0, 0);
        sacc[tile] = __builtin_amdgcn_mfma_f32_16x16x32_bf16(aq1, b1, sacc[tile], 0, 0, 0);
    }

    // ---- softmax: row = quad*4 + r; 16 lanes sharing `quad` hold a row
    const float scale = 0.125f;
    float mrow[4], lrow[4];
#pragma unroll
    for (int r = 0; r < 4; r++) mrow[r] = -1e30f;
#pragma unroll
    for (int tile = 0; tile < 14; tile++) {
        int col = tile * 16 + l16;
        bool valid = (col < NTOK);
#pragma unroll
        for (int r = 0; r < 4; r++) {
            float s = valid ? sacc[tile][r] * scale : -1e30f;
            sacc[tile][r] = s;
            mrow[r] = fmaxf(mrow[r], s);
        }
    }
#pragma unroll
    for (int r = 0; r < 4; r++) {
        for (int m = 1; m < 16; m <<= 1)
            mrow[r] = fmaxf(mrow[r], __shfl_xor(mrow[r], m));
        lrow[r] = 0.f;
    }
#pragma unroll
    for (int tile = 0; tile < 14; tile++) {
#pragma unroll
        for (int r = 0; r < 4; r++) {
            float p = expf(sacc[tile][r] - mrow[r]);
            sacc[tile][r] = p;
            lrow[r] += p;
        }
    }
#pragma unroll
    for (int r = 0; r < 4; r++) {
        for (int m = 1; m < 16; m <<= 1)
            lrow[r] += __shfl_xor(lrow[r], m);
        lrow[r] = 1.f / lrow[r];
    }

    // all waves must finish reading sKP (K) before P overwrites it
    __syncthreads();

    // ---- write normalized P (bf16) into per-wave aliased region, skewed rows
    ushort_t* sp = sKP + wave * (16 * SV_ST + 16);
#pragma unroll
    for (int tile = 0; tile < 14; tile++) {
        int col = tile * 16 + l16;
#pragma unroll
        for (int r = 0; r < 4; r++) {
            int m = quad * 4 + r;
            sp[m * SV_ST + (m >> 3) * 8 + col] = f2bf(sacc[tile][r] * lrow[r]);
        }
    }
    // wave-local: LDS writes->reads ordered by lgkmcnt within the wave

    // ---- O = P V : A = sp, B = sVt; 7 k-steps of 32 keys
    floatx4 oacc[4];
#pragma unroll
    for (int i = 0; i < 4; i++) oacc[i] = (floatx4){0.f, 0.f, 0.f, 0.f};
#pragma unroll
    for (int ks = 0; ks < 7; ks++) {
        bf16x8 ap = *(const bf16x8*)(sp + l16 * SV_ST + (l16 >> 3) * 8 + ks * 32 + quad * 8);
#pragma unroll
        for (int nt = 0; nt < 4; nt++) {
            bf16x8 bv = *(const bf16x8*)(sVt + vt_row(nt * 16 + l16) + ks * 32 + quad * 8);
            oacc[nt] = __builtin_amdgcn_mfma_f32_16x16x32_bf16(ap, bv, oacc[nt], 0, 0, 0);
        }
    }
    // ---- write O (bf16) token-major [197*b + row][768]
    int orow0 = i0 + wave * 16 + quad * 4;
#pragma unroll
    for (int nt = 0; nt < 4; nt++) {
        int col = h * 64 + nt * 16 + l16;
#pragma unroll
        for (int r = 0; r < 4; r++) {
            int row = orow0 + r;
            if (row < NTOK)
                O[((long)b * NTOK + row) * DD + col] = f2bf(oacc[nt][r]);
        }
    }
}

// ---------------------------------------------------------------------------
// fp32 NT GEMM (small shapes: proj/head). flags: 1=bias
// ---------------------------------------------------------------------------
__global__ void gemm_nt(const float* __restrict__ A, int lda,
                        const float* __restrict__ W, int ldw,
                        const float* __restrict__ bias,
                        float* __restrict__ C, int ldc,
                        int M, int Nout, int K, int flags)
{
    __shared__ float sA[16][65];
    __shared__ float sW[16][65];
    const int tx = threadIdx.x, ty = threadIdx.y;
    const int t = ty * 16 + tx;
    const int m0 = blockIdx.y * 64, n0 = blockIdx.x * 64;
    float acc[4][4] = {};

    for (int kt = 0; kt < K; kt += 16) {
#pragma unroll
        for (int s = 0; s < 4; s++) {
            int e = t + s * 256;
            int r = e >> 4, c = e & 15;
            int gm = m0 + r, gn = n0 + r, gk = kt + c;
            sA[c][r] = (gm < M) ? A[(long)gm * lda + gk] : 0.f;
            sW[c][r] = (gn < Nout) ? W[(long)gn * ldw + gk] : 0.f;
        }
        __syncthreads();
#pragma unroll
        for (int kk = 0; kk < 16; kk++) {
            float a[4], b[4];
#pragma unroll
            for (int i = 0; i < 4; i++) a[i] = sA[kk][ty + 16 * i];
#pragma unroll
            for (int j = 0; j < 4; j++) b[j] = sW[kk][tx + 16 * j];
#pragma unroll
            for (int i = 0; i < 4; i++)
#pragma unroll
                for (int j = 0; j < 4; j++)
                    acc[i][j] += a[i] * b[j];
        }
        __syncthreads();
    }
#pragma unroll
    for (int i = 0; i < 4; i++) {
        int m = m0 + ty + 16 * i;
        if (m >= M) continue;
#pragma unroll
        for (int j = 0; j < 4; j++) {
            int n = n0 + tx + 16 * j;
            if (n >= Nout) continue;
            float v = acc[i][j];
            if (flags & 1) v += bias[n];
            C[(long)m * ldc + n] = v;
        }
    }
}

// ---------------------------------------------------------------------------
// fp32 -> bf16 bulk convert (n % 4 == 0)
// ---------------------------------------------------------------------------
__global__ void f32_to_bf16(const float* __restrict__ in, ushort_t* __restrict__ out, long n)
{
    long i = ((long)blockIdx.x * 256 + threadIdx.x) * 4;
    if (i >= n) return;
    float4 v = *(const float4*)(in + i);
    ushort4 o;
    o.x = f2bf(v.x); o.y = f2bf(v.y); o.z = f2bf(v.z); o.w = f2bf(v.w);
    *(ushort4*)(out + i) = o;
}

// ---------------------------------------------------------------------------
// LayerNorm over last dim (768), fp32 out.
// ---------------------------------------------------------------------------
__global__ void layernorm_rows(const float* __restrict__ X,
                               const float* __restrict__ w,
                               const float* __restrict__ b,
                               float* __restrict__ Y)
{
    const int r = blockIdx.x;
    const int t = threadIdx.x;
    const float* xr = X + (long)r * DD;
    float x0 = xr[t], x1 = xr[t + 256], x2 = xr[t + 512];
    __shared__ float rs[256], rq[256];
    rs[t] = x0 + x1 + x2;
    rq[t] = x0 * x0 + x1 * x1 + x2 * x2;
    __syncthreads();
    for (int off = 128; off > 0; off >>= 1) {
        if (t < off) { rs[t] += rs[t + off]; rq[t] += rq[t + off]; }
        __syncthreads();
    }
    float mean = rs[0] * (1.f / 768.f);
    float var = rq[0] * (1.f / 768.f) - mean * mean;
    float rstd = rsqrtf(var + 1e-5f);
    float* yr = Y + (long)r * DD;
    yr[t]       = (x0 - mean) * rstd * w[t]       + b[t];
    yr[t + 256] = (x1 - mean) * rstd * w[t + 256] + b[t + 256];
    yr[t + 512] = (x2 - mean) * rstd * w[t + 512] + b[t + 512];
}

// LayerNorm, bf16 out.
__global__ void layernorm_rows_bf16(const float* __restrict__ X,
                                    const float* __restrict__ w,
                                    const float* __restrict__ b,
                                    ushort_t* __restrict__ Y)
{
    const int r = blockIdx.x;
    const int t = threadIdx.x;
    const float* xr = X + (long)r * DD;
    float x0 = xr[t], x1 = xr[t + 256], x2 = xr[t + 512];
    __shared__ float rs[256], rq[256];
    rs[t] = x0 + x1 + x2;
    rq[t] = x0 * x0 + x1 * x1 + x2 * x2;
    __syncthreads();
    for (int off = 128; off > 0; off >>= 1) {
        if (t < off) { rs[t] += rs[t + off]; rq[t] += rq[t + off]; }
        __syncthreads();
    }
    float mean = rs[0] * (1.f / 768.f);
    float var = rq[0] * (1.f / 768.f) - mean * mean;
    float rstd = rsqrtf(var + 1e-5f);
    ushort_t* yr = Y + (long)r * DD;
    yr[t]       = f2bf((x0 - mean) * rstd * w[t]       + b[t]);
    yr[t + 256] = f2bf((x1 - mean) * rstd * w[t + 256] + b[t + 256]);
    yr[t + 512] = f2bf((x2 - mean) * rstd * w[t + 512] + b[t + 512]);
}

// LayerNorm of cls rows only -> pooled (B,768) fp32
__global__ void ln_post_cls(const float* __restrict__ X,
                            const float* __restrict__ w,
                            const float* __restrict__ b,
                            float* __restrict__ pooled)
{
    const int bidx = blockIdx.x;
    const int t = threadIdx.x;
    const float* xr = X + (long)bidx * NTOK * DD;
    float x0 = xr[t], x1 = xr[t + 256], x2 = xr[t + 512];
    __shared__ float rs[256], rq[256];
    rs[t] = x0 + x1 + x2;
    rq[t] = x0 * x0 + x1 * x1 + x2 * x2;
    __syncthreads();
    for (int off = 128; off > 0; off >>= 1) {
        if (t < off) { rs[t] += rs[t + off]; rq[t] += rq[t + off]; }
        __syncthreads();
    }
    float mean = rs[0] * (1.f / 768.f);
    float var = rq[0] * (1.f / 768.f) - mean * mean;
    float rstd = rsqrtf(var + 1e-5f);
    float* yr = pooled + (long)bidx * DD;
    yr[t]       = (x0 - mean) * rstd * w[t]       + b[t];
    yr[t + 256] = (x1 - mean) * rstd * w[t + 256] + b[t + 256];
    yr[t + 512] = (x2 - mean) * rstd * w[t + 512] + b[t + 512];
}

// ---------------------------------------------------------------------------
// im2col -> bf16: x (B,C,224,224) -> patches (B*196, 768)
// ---------------------------------------------------------------------------
__global__ void im2col_bf16(const float* __restrict__ x, ushort_t* __restrict__ Pm)
{
    int idx = blockIdx.x * 256 + threadIdx.x;
    const int total = BB * NPATCH * DD;
    if (idx >= total) return;
    int row = idx / DD;
    int k = idx - row * DD;
    int b = row / NPATCH;
    int p = row - b * NPATCH;
    int py = p / 14, px = p - py * 14;
    int c = k >> 8;
    int rr = k & 255;
    int ph = rr >> 4, pw = rr & 15;
    Pm[idx] = f2bf(x[(((long)b * CC + c) * IMG + (py * 16 + ph)) * IMG + (px * 16 + pw)]);
}

// ---------------------------------------------------------------------------
// assemble: Tmp[b,n,:] = (n==0 ? cls : patch_out[b,n-1,:]) + pos_embed[n,:]
// ---------------------------------------------------------------------------
__global__ void assemble_kernel(const float* __restrict__ tmp,
                                const float* __restrict__ cls,
                                const float* __restrict__ pos,
                                float* __restrict__ Hb)
{
    int idx = blockIdx.x * 256 + threadIdx.x;
    const int total = MTOK * DD;
    if (idx >= total) return;
    int row = idx / DD;
    int d = idx - row * DD;
    int b = row / NTOK;
    int n = row - b * NTOK;
    float v = (n == 0) ? cls[d] : tmp[((long)b * NPATCH + (n - 1)) * DD + d];
    Hb[idx] = v + pos[n * DD + d];
}

// ---------------------------------------------------------------------------
extern "C" void kernel_launch(void* const* d_in, const int* in_sizes, int n_in,
                              void* d_out, int out_size, void* d_ws, size_t ws_size,
                              hipStream_t stream)
{
    const float* x          = (const float*)d_in[0];
    const float* conv_w     = (const float*)d_in[1];
    const float* cls_token  = (const float*)d_in[2];
    const float* pos_embed  = (const float*)d_in[3];
    const float* ln_pre_w   = (const float*)d_in[4];
    const float* ln_pre_b   = (const float*)d_in[5];
    const float* ln1_w      = (const float*)d_in[6];
    const float* ln1_b      = (const float*)d_in[7];
    const float* qkv_w      = (const float*)d_in[8];
    const float* qkv_b      = (const float*)d_in[9];
    const float* attn_pw    = (const float*)d_in[10];
    const float* attn_pb    = (const float*)d_in[11];
    const float* ln2_w      = (const float*)d_in[12];
    const float* ln2_b      = (const float*)d_in[13];
    const float* fc_w       = (const float*)d_in[14];
    const float* fc_b       = (const float*)d_in[15];
    const float* cproj_w    = (const float*)d_in[16];
    const float* cproj_b    = (const float*)d_in[17];
    const float* ln_post_w  = (const float*)d_in[18];
    const float* ln_post_b  = (const float*)d_in[19];
    const float* proj_w     = (const float*)d_in[20];
    const float* head_w     = (const float*)d_in[21];
    const float* head_b     = (const float*)d_in[22];
    float* out = (float*)d_out;

    // -------- workspace layout --------
    char* ws = (char*)d_ws;
    size_t off = 0;
    float*    X     = (float*)(ws + off);    off += (size_t)MPAD * DD * 4;        // residual (fp32)
    ushort_t* Hb    = (ushort_t*)(ws + off); off += (size_t)MPAD * DD * 2;        // bf16 activations
    ushort_t* QKVb  = (ushort_t*)(ws + off); off += (size_t)MPAD * 2304 * 2;      // bf16 qkv
    ushort_t* Hmlp  = (ushort_t*)(ws + off); off += (size_t)MPAD * MLPD * 2;      // bf16 mlp / im2col
    float*    ScF   = (float*)(ws + off);    off += (size_t)(BB * NPATCH) * DD * 4; // patch gemm out
    float*    TmpF  = (float*)(ws + off);    off += (size_t)MPAD * DD * 4;        // assemble out
    ushort_t* Wb    = (ushort_t*)(ws + off); off += (size_t)85524480 * 2;         // bf16 weights
    float*  pooled  = (float*)(ws + off);    off += (size_t)BB * DD * 4;
    float*  z       = (float*)(ws + off);    off += (size_t)BB * PROJD * 4;

    ushort_t* convb  = Wb;
    ushort_t* qkvb   = convb  + 589824;
    ushort_t* aprojb = qkvb   + 21233664;
    ushort_t* fcb    = aprojb + 7077888;
    ushort_t* cprojb = fcb    + 28311552;

    // -------- weight conversions --------
    {
        long n;
        n = 589824;   f32_to_bf16<<<(n / 4 + 255) / 256, 256, 0, stream>>>(conv_w,  convb,  n);
        n = 21233664; f32_to_bf16<<<(n / 4 + 255) / 256, 256, 0, stream>>>(qkv_w,   qkvb,   n);
        n = 7077888;  f32_to_bf16<<<(n / 4 + 255) / 256, 256, 0, stream>>>(attn_pw, aprojb, n);
        n = 28311552; f32_to_bf16<<<(n / 4 + 255) / 256, 256, 0, stream>>>(fc_w,    fcb,    n);
        n = 28311552; f32_to_bf16<<<(n / 4 + 255) / 256, 256, 0, stream>>>(cproj_w, cprojb, n);
    }

    // -------- patch embed --------
    {
        int tot = BB * NPATCH * DD;
        im2col_bf16<<<(tot + 255) / 256, 256, 0, stream>>>(x, Hmlp);
        gemm_bf16_n64<<<dim3(DD / 64, 49), 256, 0, stream>>>(
            Hmlp, DD, convb, DD, nullptr, ScF, DD, DD, 0);
        int tot2 = MTOK * DD;
        assemble_kernel<<<(tot2 + 255) / 256, 256, 0, stream>>>(ScF, cls_token, pos_embed, TmpF);
        layernorm_rows<<<MTOK, 256, 0, stream>>>(TmpF, ln_pre_w, ln_pre_b, X);
    }

    // -------- transformer blocks --------
    for (int l = 0; l < NLAYER; l++) {
        layernorm_rows_bf16<<<MTOK, 256, 0, stream>>>(X, ln1_w + l * DD, ln1_b + l * DD, Hb);
        gemm_bf16<<<dim3(2304 / 128, MPAD / 128), 256, 0, stream>>>(
            Hb, DD, qkvb + (long)l * 2304 * DD, DD, qkv_b + l * 2304,
            QKVb, 2304, DD, 1 | 8);
        attn_fused<<<dim3(4, BB * NH), 256, 0, stream>>>(QKVb, Hb);
        gemm_bf16_n64<<<dim3(DD / 64, MPAD / 128), 256, 0, stream>>>(
            Hb, DD, aprojb + (long)l * DD * DD, DD, attn_pb + l * DD,
            X, DD, DD, 1 | 4);
        layernorm_rows_bf16<<<MTOK, 256, 0, stream>>>(X, ln2_w + l * DD, ln2_b + l * DD, Hb);
        gemm_bf16<<<dim3(MLPD / 128, MPAD / 128), 256, 0, stream>>>(
            Hb, DD, fcb + (long)l * MLPD * DD, DD, fc_b + l * MLPD,
            Hmlp, MLPD, DD, 1 | 2 | 8);
        gemm_bf16_n64<<<dim3(DD / 64, MPAD / 128), 256, 0, stream>>>(
            Hmlp, MLPD, cprojb + (long)l * DD * MLPD, MLPD, cproj_b + l * DD,
            X, DD, MLPD, 1 | 4);
    }

    // -------- head --------
    ln_post_cls<<<BB, 256, 0, stream>>>(X, ln_post_w, ln_post_b, pooled);
    gemm_nt<<<dim3(PROJD / 64, 1), dim3(16, 16), 0, stream>>>(
        pooled, DD, proj_w, DD, nullptr, z, PROJD, BB, PROJD, DD, 0);
    gemm_nt<<<dim3((NCLS + 63) / 64, 1), dim3(16, 16), 0, stream>>>(
        z, PROJD, head_w, PROJD, head_b, out, NCLS, BB, NCLS, PROJD, 1);
}